// Round 4
// baseline (132.183 us; speedup 1.0000x reference)
//
#include <hip/hip_runtime.h>
#include <hip/hip_bf16.h>
#include <cstdint>
#include <cstddef>

typedef __attribute__((ext_vector_type(8))) short short8;
typedef __attribute__((ext_vector_type(4))) short short4v;
typedef __attribute__((ext_vector_type(4))) float f32x4;

#define HH 12
#define DD 64
#define NN 2048
#define CC 768

__device__ __forceinline__ float bf2f(short s) {
  union { uint32_t u; float f; } v;
  v.u = ((uint32_t)(uint16_t)s) << 16;
  return v.f;
}
__device__ __forceinline__ short f2bf(float f) {
  union { float f; uint32_t u; } v; v.f = f;
  uint32_t r = v.u + 0x7FFFu + ((v.u >> 16) & 1u);
  return (short)(r >> 16);
}
__device__ __forceinline__ uint32_t pack2bf(float a, float b) {
  return ((uint32_t)(uint16_t)f2bf(b) << 16) | (uint32_t)(uint16_t)f2bf(a);
}

// ---------------------------------------------------------------------------
// Normalizer: fp32 -> bf16 for x, w_qkv, w_out.
// Block ranges: x:[0,1536) wqkv:[1536,2400) wout:[2400,2688)
// ---------------------------------------------------------------------------
__global__ __launch_bounds__(256)
void norm_k(const float* __restrict__ s0, const float* __restrict__ s1,
            const float* __restrict__ s2,
            short* __restrict__ d0, short* __restrict__ d1,
            short* __restrict__ d2)
{
  const int bid = blockIdx.x;
  const float* src; short* dst; int base;
  if (bid < 1536)      { src = s0; dst = d0; base = bid; }
  else if (bid < 2400) { src = s1; dst = d1; base = bid - 1536; }
  else                 { src = s2; dst = d2; base = bid - 2400; }
  const int idx = (base * 256 + (int)threadIdx.x) * 8;
  const float* sf = src + idx;
  f32x4 a = *(const f32x4*)sf;
  f32x4 b = *(const f32x4*)(sf + 4);
  short8 o;
  o[0] = f2bf(a[0]); o[1] = f2bf(a[1]); o[2] = f2bf(a[2]); o[3] = f2bf(a[3]);
  o[4] = f2bf(b[0]); o[5] = f2bf(b[1]); o[6] = f2bf(b[2]); o[7] = f2bf(b[3]);
  *(short8*)(dst + idx) = o;
}

// ---------------------------------------------------------------------------
// GEMM: C[m,f] = sum_c A[m,c] * W[f,c]   (A: [4096,768], W: [F,768], bf16)
// MODE 0: F=2304, split epilogue -> Q (x0.125) [b,h,n,d], K [b,h,n,d], V^T [b,h,d,n]
// MODE 1: F=768, epilogue -> Of[m*768+f] = C + bias[f]  (fp32 out)
// ---------------------------------------------------------------------------
template <int MODE>
__global__ __launch_bounds__(256, 2)
void gemm_k(const short* __restrict__ A, const short* __restrict__ W,
            const float* __restrict__ bias,
            short* __restrict__ O0, short* __restrict__ O1, short* __restrict__ O2,
            float* __restrict__ Of)
{
  __shared__ __align__(16) short lA[128 * 64];
  __shared__ __align__(16) short lB[128 * 64];
  const int tid = threadIdx.x;
  const int w = tid >> 6, l = tid & 63;
  const int lq = l & 15, lh = l >> 4;
  const int m0 = blockIdx.y * 128;
  const int f0 = blockIdx.x * 128;
  const int seg = tid & 7;
  const int rbase = tid >> 3;

  f32x4 acc[4][4] = {};

  for (int kb = 0; kb < CC; kb += 64) {
    __syncthreads();
#pragma unroll
    for (int j = 0; j < 4; ++j) {
      const int row = j * 32 + rbase;
      const int dst = row * 128 + ((seg * 16) ^ ((row & 7) << 4));
      *(short8*)((char*)lA + dst) =
          *(const short8*)(A + (size_t)(m0 + row) * CC + kb + seg * 8);
      *(short8*)((char*)lB + dst) =
          *(const short8*)(W + (size_t)(f0 + row) * CC + kb + seg * 8);
    }
    __syncthreads();
    const int wr = (w >> 1) * 64, wc = (w & 1) * 64;
#pragma unroll
    for (int c = 0; c < 2; ++c) {
      short8 af[4], bfr[4];
#pragma unroll
      for (int i = 0; i < 4; ++i) {
        const int rowA = wr + i * 16 + lq;
        af[i] = *(const short8*)((char*)lA + rowA * 128 +
                                 ((c * 64 + lh * 16) ^ ((rowA & 7) << 4)));
        const int rowB = wc + i * 16 + lq;
        bfr[i] = *(const short8*)((char*)lB + rowB * 128 +
                                  ((c * 64 + lh * 16) ^ ((rowB & 7) << 4)));
      }
#pragma unroll
      for (int mi = 0; mi < 4; ++mi)
#pragma unroll
        for (int ni = 0; ni < 4; ++ni)
          acc[mi][ni] = __builtin_amdgcn_mfma_f32_16x16x32_bf16(
              af[mi], bfr[ni], acc[mi][ni], 0, 0, 0);
    }
  }

  const int wr = (w >> 1) * 64, wc = (w & 1) * 64;
#pragma unroll
  for (int ni = 0; ni < 4; ++ni) {
    const int fb = f0 + wc + ni * 16;
    if (MODE == 0) {
      const int which = fb / CC;          // uniform per fragment
      const int hd = fb - which * CC;
      const int h = hd >> 6;              // uniform
      const int d = (hd & 63) + lq;
#pragma unroll
      for (int mi = 0; mi < 4; ++mi) {
        const int mb = m0 + wr + mi * 16 + 4 * lh;
        const int b = mb >> 11;
        const int n = mb & 2047;
        if (which == 0) {
#pragma unroll
          for (int r = 0; r < 4; ++r)
            O0[(((size_t)(b * HH + h) * NN) + n + r) * DD + d] =
                f2bf(acc[mi][ni][r] * 0.125f);
        } else if (which == 1) {
#pragma unroll
          for (int r = 0; r < 4; ++r)
            O1[(((size_t)(b * HH + h) * NN) + n + r) * DD + d] =
                f2bf(acc[mi][ni][r]);
        } else {
          short4v pk;
#pragma unroll
          for (int r = 0; r < 4; ++r) pk[r] = f2bf(acc[mi][ni][r]);
          *(short4v*)(O2 + ((size_t)(b * HH + h) * DD + d) * NN + n) = pk;
        }
      }
    } else {
      const float bv = bias[fb + lq];
#pragma unroll
      for (int mi = 0; mi < 4; ++mi) {
        const int mb = m0 + wr + mi * 16 + 4 * lh;
#pragma unroll
        for (int r = 0; r < 4; ++r)
          Of[(size_t)(mb + r) * CC + fb + lq] = acc[mi][ni][r] + bv;
      }
    }
  }
}

// ---------------------------------------------------------------------------
// colsumV[bh,d] = sum_n V[bh,n,d]  (from V^T [bh,d,n])
// ---------------------------------------------------------------------------
__global__ __launch_bounds__(256)
void colsum_k(const short* __restrict__ VT, float* __restrict__ cs)
{
  const int bh = blockIdx.x, t = threadIdx.x;
  const int d = t >> 2, part = t & 3;
  const short* p = VT + ((size_t)bh * DD + d) * NN + part * 512;
  float s = 0.f;
  for (int i = 0; i < 512; i += 8) {
    short8 v = *(const short8*)(p + i);
#pragma unroll
    for (int e = 0; e < 8; ++e) s += bf2f(v[e]);
  }
  s += __shfl_xor(s, 1);
  s += __shfl_xor(s, 2);
  if (part == 0) cs[bh * DD + d] = s;
}

// ---------------------------------------------------------------------------
// Attention, single sweep.  Per wave: 16 queries.  Swapped QK^T (lane owns
// query lane&15).  Second softmax linearized: out = (csV + P1/l1)/(2048+s1/l1)
// P1 = sum_k mf*e^s * v_k ; mf = 0.5 iff (key-q)%512==0.
// exp input clamped to <=30: NaN/inf impossible for finite inputs.
// ---------------------------------------------------------------------------
__global__ __launch_bounds__(256, 2)
void attn_k(const short* __restrict__ Qb, const short* __restrict__ Kb,
            const short* __restrict__ VT, const float* __restrict__ cs,
            short* __restrict__ AO)
{
  __shared__ __align__(16) short lK[64 * 64];   // [key][d]  (XOR-swizzled rows)
  __shared__ __align__(16) short lV[64 * 64];   // [d][key]  (XOR-swizzled rows)
  const int tid = threadIdx.x;
  const int w = tid >> 6, l = tid & 63;
  const int lq = l & 15, lh = l >> 4;
  const int bh = blockIdx.x >> 5;
  const int qblk = blockIdx.x & 31;
  const int q0 = qblk * 64 + w * 16;
  const short* Qh = Qb + (size_t)bh * NN * DD;
  const short* Kh = Kb + (size_t)bh * NN * DD;
  const short* Vh = VT + (size_t)bh * DD * NN;
  const int qg = q0 + lq;

  short8 qf[2];
#pragma unroll
  for (int c = 0; c < 2; ++c)
    qf[c] = *(const short8*)(Qh + (size_t)(q0 + lq) * DD + c * 32 + lh * 8);

  f32x4 pv[4] = {};
  float l1 = 0.f, s1 = 0.f;

  const int seg = tid & 7;
  const int rbase = tid >> 3;
  const int src0 = lq + (((2 * lh) & 3) << 4);
  const int src1 = lq + (((2 * lh + 1) & 3) << 4);
  const bool hi = (lh >> 1) != 0;

  for (int kb = 0; kb < NN; kb += 64) {
    __syncthreads();
#pragma unroll
    for (int j = 0; j < 2; ++j) {
      const int row = j * 32 + rbase;
      const int dst = row * 128 + ((seg * 16) ^ ((row & 7) << 4));
      *(short8*)((char*)lK + dst) =
          *(const short8*)(Kh + (size_t)(kb + row) * DD + seg * 8);
      *(short8*)((char*)lV + dst) =
          *(const short8*)(Vh + (size_t)row * NN + kb + seg * 8);
    }
    __syncthreads();

    // QK^T (swapped): sacc[kg][r] = S[key = kb+16*kg+4*lh+r, q = q0+lq]
    f32x4 sacc[4] = {};
#pragma unroll
    for (int c = 0; c < 2; ++c) {
#pragma unroll
      for (int kg = 0; kg < 4; ++kg) {
        const int rowK = kg * 16 + lq;
        short8 kf = *(const short8*)((char*)lK + rowK * 128 +
                                     ((c * 64 + lh * 16) ^ ((lq & 7) << 4)));
        sacc[kg] = __builtin_amdgcn_mfma_f32_16x16x32_bf16(kf, qf[c], sacc[kg], 0, 0, 0);
      }
    }

    // elementwise: e = exp(min(s,30)); masked *0.5; accumulate l1, s1; pack bf16
    uint32_t dw[4][2];
#pragma unroll
    for (int kg = 0; kg < 4; ++kg) {
      float uv[4];
#pragma unroll
      for (int r = 0; r < 4; ++r) {
        const int key = kb + kg * 16 + 4 * lh + r;
        const float e = __expf(fminf(sacc[kg][r], 30.f));
        l1 += e;
        const float u = (((key - qg) & 511) == 0) ? 0.5f * e : e;
        s1 += u;
        uv[r] = u;
      }
      dw[kg][0] = pack2bf(uv[0], uv[1]);
      dw[kg][1] = pack2bf(uv[2], uv[3]);
    }

    // Redistribute u into PV A-fragments via shuffles, then PV MFMAs
#pragma unroll
    for (int c = 0; c < 2; ++c) {
      const int g = 2 * c;
      const uint32_t w0a = __shfl((int)dw[g][0], src0),
                     w0b = __shfl((int)dw[g + 1][0], src0);
      const uint32_t w1a = __shfl((int)dw[g][1], src0),
                     w1b = __shfl((int)dw[g + 1][1], src0);
      const uint32_t w2a = __shfl((int)dw[g][0], src1),
                     w2b = __shfl((int)dw[g + 1][0], src1);
      const uint32_t w3a = __shfl((int)dw[g][1], src1),
                     w3b = __shfl((int)dw[g + 1][1], src1);
      union { uint32_t u[4]; short8 s; } pa;
      pa.u[0] = hi ? w0b : w0a;
      pa.u[1] = hi ? w1b : w1a;
      pa.u[2] = hi ? w2b : w2a;
      pa.u[3] = hi ? w3b : w3a;
#pragma unroll
      for (int dg = 0; dg < 4; ++dg) {
        const int rowV = dg * 16 + lq;
        short8 vf = *(const short8*)((char*)lV + rowV * 128 +
                                     ((c * 64 + lh * 16) ^ ((lq & 7) << 4)));
        pv[dg] = __builtin_amdgcn_mfma_f32_16x16x32_bf16(pa.s, vf, pv[dg], 0, 0, 0);
      }
    }
  }

  // full-row l1, s1 for q = lq
  l1 += __shfl_xor(l1, 16); l1 += __shfl_xor(l1, 32);
  s1 += __shfl_xor(s1, 16); s1 += __shfl_xor(s1, 32);

  const int b = bh / HH, h = bh - b * HH;
#pragma unroll
  for (int r = 0; r < 4; ++r) {
    const int qrow = 4 * lh + r;                 // row within the 16-query tile
    const float l1r = __shfl(l1, qrow);
    const float s1r = __shfl(s1, qrow);
    const float rden = 1.f / (2048.f * l1r + s1r);
    const int n = q0 + qrow;
#pragma unroll
    for (int dg = 0; dg < 4; ++dg) {
      const int d = dg * 16 + lq;
      const float csv = cs[bh * DD + d];
      const float val = (csv * l1r + pv[dg][r]) * rden;
      AO[((size_t)(b * NN + n)) * CC + h * DD + d] = f2bf(val);
    }
  }
}

// ---------------------------------------------------------------------------
extern "C" void kernel_launch(void* const* d_in, const int* in_sizes, int n_in,
                              void* d_out, int out_size, void* d_ws, size_t ws_size,
                              hipStream_t stream)
{
  (void)in_sizes; (void)n_in; (void)out_size;
  float* out = (float*)d_out;

  const size_t HD = (size_t)2 * HH * NN * DD;   // 3,145,728 elements
  const size_t NX = 3145728, NW = 1769472, NO = 589824;
  const size_t need = (4 * HD + NX + NW + NO) * sizeof(short)
                    + (size_t)2 * HH * DD * sizeof(float) + 64;
  if (ws_size < need) return;   // diagnostic: zero output -> absmax == max|ref|

  short* Qb = (short*)d_ws;
  short* Kb = Qb + HD;
  short* VT = Kb + HD;
  short* AO = VT + HD;
  float* cs = (float*)(AO + HD);
  short* xb  = (short*)(cs + 2 * HH * DD);
  short* wqb = xb + NX;
  short* wob = wqb + NW;

  dim3 blk(256);
  norm_k<<<dim3(2688), blk, 0, stream>>>((const float*)d_in[0],
                                         (const float*)d_in[1],
                                         (const float*)d_in[2],
                                         xb, wqb, wob);
  gemm_k<0><<<dim3(2304 / 128, 4096 / 128), blk, 0, stream>>>(
      xb, wqb, nullptr, Qb, Kb, VT, nullptr);
  colsum_k<<<dim3(2 * HH), blk, 0, stream>>>(VT, cs);
  attn_k<<<dim3(2 * HH * (NN / 64)), blk, 0, stream>>>(Qb, Kb, VT, cs, AO);
  gemm_k<1><<<dim3(CC / 128, 4096 / 128), blk, 0, stream>>>(
      AO, wob, (const float*)d_in[3], nullptr, nullptr, nullptr, out);
}

// Round 5
// 122.925 us; speedup vs baseline: 1.0753x; 1.0753x over previous
//
#include <hip/hip_runtime.h>
#include <hip/hip_bf16.h>
#include <cstdint>
#include <cstddef>

typedef __attribute__((ext_vector_type(8))) short short8;
typedef __attribute__((ext_vector_type(4))) short short4v;
typedef __attribute__((ext_vector_type(4))) float f32x4;

#define HH 12
#define DD 64
#define NN 2048
#define CC 768
// 0.125 (HEAD_DIM^-0.5) * log2(e): lets attn use exp2 directly.
#define QSCALE 0.18033688011112042f

__device__ __forceinline__ float bf2f(short s) {
  union { uint32_t u; float f; } v;
  v.u = ((uint32_t)(uint16_t)s) << 16;
  return v.f;
}
__device__ __forceinline__ short f2bf(float f) {
  union { float f; uint32_t u; } v; v.f = f;
  uint32_t r = v.u + 0x7FFFu + ((v.u >> 16) & 1u);
  return (short)(r >> 16);
}
// packed f32x2 -> bf16x2 (low = a, high = b) in one instruction
__device__ __forceinline__ uint32_t cvtpk(float a, float b) {
  uint32_t r;
  asm("v_cvt_pk_bf16_f32 %0, %1, %2" : "=v"(r) : "v"(a), "v"(b));
  return r;
}

// ---------------------------------------------------------------------------
// Normalizer: fp32 -> bf16 for x, w_qkv, w_out.
// ---------------------------------------------------------------------------
__global__ __launch_bounds__(256)
void norm_k(const float* __restrict__ s0, const float* __restrict__ s1,
            const float* __restrict__ s2,
            short* __restrict__ d0, short* __restrict__ d1,
            short* __restrict__ d2)
{
  const int bid = blockIdx.x;
  const float* src; short* dst; int base;
  if (bid < 1536)      { src = s0; dst = d0; base = bid; }
  else if (bid < 2400) { src = s1; dst = d1; base = bid - 1536; }
  else                 { src = s2; dst = d2; base = bid - 2400; }
  const int idx = (base * 256 + (int)threadIdx.x) * 8;
  const float* sf = src + idx;
  f32x4 a = *(const f32x4*)sf;
  f32x4 b = *(const f32x4*)(sf + 4);
  short8 o;
  o[0] = f2bf(a[0]); o[1] = f2bf(a[1]); o[2] = f2bf(a[2]); o[3] = f2bf(a[3]);
  o[4] = f2bf(b[0]); o[5] = f2bf(b[1]); o[6] = f2bf(b[2]); o[7] = f2bf(b[3]);
  *(short8*)(dst + idx) = o;
}

// ---------------------------------------------------------------------------
// GEMM: C[m,f] = sum_c A[m,c] * W[f,c]   (A: [4096,768], W: [F,768], bf16)
// MODE 0: F=2304 -> Q (x QSCALE) [b,h,n,d], K [b,h,n,d], V^T [b,h,d,n]
// MODE 1: F=768 -> Of[m*768+f] = C + bias[f]  (fp32 out)
// ---------------------------------------------------------------------------
template <int MODE>
__global__ __launch_bounds__(256, 2)
void gemm_k(const short* __restrict__ A, const short* __restrict__ W,
            const float* __restrict__ bias,
            short* __restrict__ O0, short* __restrict__ O1, short* __restrict__ O2,
            float* __restrict__ Of)
{
  __shared__ __align__(16) short lA[128 * 64];
  __shared__ __align__(16) short lB[128 * 64];
  const int tid = threadIdx.x;
  const int w = tid >> 6, l = tid & 63;
  const int lq = l & 15, lh = l >> 4;
  const int m0 = blockIdx.y * 128;
  const int f0 = blockIdx.x * 128;
  const int seg = tid & 7;
  const int rbase = tid >> 3;

  f32x4 acc[4][4] = {};

  for (int kb = 0; kb < CC; kb += 64) {
    __syncthreads();
#pragma unroll
    for (int j = 0; j < 4; ++j) {
      const int row = j * 32 + rbase;
      const int dst = row * 128 + ((seg * 16) ^ ((row & 7) << 4));
      *(short8*)((char*)lA + dst) =
          *(const short8*)(A + (size_t)(m0 + row) * CC + kb + seg * 8);
      *(short8*)((char*)lB + dst) =
          *(const short8*)(W + (size_t)(f0 + row) * CC + kb + seg * 8);
    }
    __syncthreads();
    const int wr = (w >> 1) * 64, wc = (w & 1) * 64;
#pragma unroll
    for (int c = 0; c < 2; ++c) {
      short8 af[4], bfr[4];
#pragma unroll
      for (int i = 0; i < 4; ++i) {
        const int rowA = wr + i * 16 + lq;
        af[i] = *(const short8*)((char*)lA + rowA * 128 +
                                 ((c * 64 + lh * 16) ^ ((rowA & 7) << 4)));
        const int rowB = wc + i * 16 + lq;
        bfr[i] = *(const short8*)((char*)lB + rowB * 128 +
                                  ((c * 64 + lh * 16) ^ ((rowB & 7) << 4)));
      }
#pragma unroll
      for (int mi = 0; mi < 4; ++mi)
#pragma unroll
        for (int ni = 0; ni < 4; ++ni)
          acc[mi][ni] = __builtin_amdgcn_mfma_f32_16x16x32_bf16(
              af[mi], bfr[ni], acc[mi][ni], 0, 0, 0);
    }
  }

  const int wr = (w >> 1) * 64, wc = (w & 1) * 64;
#pragma unroll
  for (int ni = 0; ni < 4; ++ni) {
    const int fb = f0 + wc + ni * 16;
    if (MODE == 0) {
      const int which = fb / CC;          // uniform per fragment
      const int hd = fb - which * CC;
      const int h = hd >> 6;              // uniform
      const int d = (hd & 63) + lq;
#pragma unroll
      for (int mi = 0; mi < 4; ++mi) {
        const int mb = m0 + wr + mi * 16 + 4 * lh;
        const int b = mb >> 11;
        const int n = mb & 2047;
        if (which == 0) {
#pragma unroll
          for (int r = 0; r < 4; ++r)
            O0[(((size_t)(b * HH + h) * NN) + n + r) * DD + d] =
                f2bf(acc[mi][ni][r] * QSCALE);
        } else if (which == 1) {
#pragma unroll
          for (int r = 0; r < 4; ++r)
            O1[(((size_t)(b * HH + h) * NN) + n + r) * DD + d] =
                f2bf(acc[mi][ni][r]);
        } else {
          short4v pk;
#pragma unroll
          for (int r = 0; r < 4; ++r) pk[r] = f2bf(acc[mi][ni][r]);
          *(short4v*)(O2 + ((size_t)(b * HH + h) * DD + d) * NN + n) = pk;
        }
      }
    } else {
      const float bv = bias[fb + lq];
#pragma unroll
      for (int mi = 0; mi < 4; ++mi) {
        const int mb = m0 + wr + mi * 16 + 4 * lh;
#pragma unroll
        for (int r = 0; r < 4; ++r)
          Of[(size_t)(mb + r) * CC + fb + lq] = acc[mi][ni][r] + bv;
      }
    }
  }
}

// ---------------------------------------------------------------------------
// colsumV[bh,d] = sum_n V[bh,n,d]  (from V^T [bh,d,n])
// ---------------------------------------------------------------------------
__global__ __launch_bounds__(256)
void colsum_k(const short* __restrict__ VT, float* __restrict__ cs)
{
  const int bh = blockIdx.x, t = threadIdx.x;
  const int d = t >> 2, part = t & 3;
  const short* p = VT + ((size_t)bh * DD + d) * NN + part * 512;
  float s = 0.f;
  for (int i = 0; i < 512; i += 8) {
    short8 v = *(const short8*)(p + i);
#pragma unroll
    for (int e = 0; e < 8; ++e) s += bf2f(v[e]);
  }
  s += __shfl_xor(s, 1);
  s += __shfl_xor(s, 2);
  if (part == 0) cs[bh * DD + d] = s;
}

// ---------------------------------------------------------------------------
// Attention sweep.  Per wave: 16 queries; swapped QK^T.  Linearized 2nd
// softmax: out = (csV*l1 + P1)/(2048*l1 + s1), s1 = l1 - 0.5*mc,
// mc = sum of e over masked keys ((key-q)%512==0) -- wave-uniform-rare.
// NSPLIT=1: direct AO write.  NSPLIT=2: fp32 partial dump (pv,l1,mc).
// PART_STRIDE floats per (block) partial record.
// ---------------------------------------------------------------------------
#define PART_STRIDE 4224
template <int NSPLIT>
__global__ __launch_bounds__(256, 2)
void attn_k(const short* __restrict__ Qb, const short* __restrict__ Kb,
            const short* __restrict__ VT, const float* __restrict__ cs,
            short* __restrict__ AO, float* __restrict__ part)
{
  __shared__ __align__(16) short lK[64 * 64];   // [key][d]  (XOR-swizzled rows)
  __shared__ __align__(16) short lV[64 * 64];   // [d][key]  (XOR-swizzled rows)
  const int tid = threadIdx.x;
  const int w = tid >> 6, l = tid & 63;
  const int lq = l & 15, lh = l >> 4;
  int bh, qblk, ks;
  if (NSPLIT == 2) {
    bh = blockIdx.x >> 6;
    qblk = (blockIdx.x & 63) >> 1;
    ks = blockIdx.x & 1;
  } else {
    bh = blockIdx.x >> 5;
    qblk = blockIdx.x & 31;
    ks = 0;
  }
  const int q0 = qblk * 64 + w * 16;
  const short* Qh = Qb + (size_t)bh * NN * DD;
  const short* Kh = Kb + (size_t)bh * NN * DD;
  const short* Vh = VT + (size_t)bh * DD * NN;
  const int qg = q0 + lq;

  short8 qf[2];
#pragma unroll
  for (int c = 0; c < 2; ++c)
    qf[c] = *(const short8*)(Qh + (size_t)(q0 + lq) * DD + c * 32 + lh * 8);

  f32x4 pv[4] = {};
  float l1 = 0.f, mc = 0.f;

  const int seg = tid & 7;
  const int rbase = tid >> 3;
  const int src0 = lq + (((2 * lh) & 3) << 4);
  const int src1 = lq + (((2 * lh + 1) & 3) << 4);
  const bool hi = (lh >> 1) != 0;

  const int kb0 = ks * (NN / NSPLIT);
  const int kb1 = kb0 + NN / NSPLIT;
  for (int kb = kb0; kb < kb1; kb += 64) {
    __syncthreads();
#pragma unroll
    for (int j = 0; j < 2; ++j) {
      const int row = j * 32 + rbase;
      const int dst = row * 128 + ((seg * 16) ^ ((row & 7) << 4));
      *(short8*)((char*)lK + dst) =
          *(const short8*)(Kh + (size_t)(kb + row) * DD + seg * 8);
      *(short8*)((char*)lV + dst) =
          *(const short8*)(Vh + (size_t)row * NN + kb + seg * 8);
    }
    __syncthreads();

    // QK^T (swapped): sacc[kg][r] = S[key = kb+16*kg+4*lh+r, q = q0+lq] * log2e
    f32x4 sacc[4] = {};
#pragma unroll
    for (int c = 0; c < 2; ++c) {
#pragma unroll
      for (int kg = 0; kg < 4; ++kg) {
        const int rowK = kg * 16 + lq;
        short8 kf = *(const short8*)((char*)lK + rowK * 128 +
                                     ((c * 64 + lh * 16) ^ ((lq & 7) << 4)));
        sacc[kg] = __builtin_amdgcn_mfma_f32_16x16x32_bf16(kf, qf[c], sacc[kg], 0, 0, 0);
      }
    }

    // elementwise: e = exp2(min(s,60)); mask handling hoisted to the rare
    // wave-uniform tile where ((q0-kb)&448)==0 (4 of 32 tiles).
    uint32_t dw[4][2];
    if (((q0 - kb) & 448) == 0) {
      const int delta = (qg - kb) & 511;      // in [0,64): this lane's masked key
#pragma unroll
      for (int kg = 0; kg < 4; ++kg) {
        float uv[4];
#pragma unroll
        for (int r = 0; r < 4; ++r) {
          const float e = __builtin_exp2f(fminf(sacc[kg][r], 60.f));
          l1 += e;
          const bool m = (kg * 16 + 4 * lh + r) == delta;
          mc += m ? e : 0.f;
          uv[r] = m ? 0.5f * e : e;
        }
        dw[kg][0] = cvtpk(uv[0], uv[1]);
        dw[kg][1] = cvtpk(uv[2], uv[3]);
      }
    } else {
#pragma unroll
      for (int kg = 0; kg < 4; ++kg) {
        float uv[4];
#pragma unroll
        for (int r = 0; r < 4; ++r) {
          const float e = __builtin_exp2f(fminf(sacc[kg][r], 60.f));
          l1 += e;
          uv[r] = e;
        }
        dw[kg][0] = cvtpk(uv[0], uv[1]);
        dw[kg][1] = cvtpk(uv[2], uv[3]);
      }
    }

    // Redistribute u into PV A-fragments via shuffles, then PV MFMAs
#pragma unroll
    for (int c = 0; c < 2; ++c) {
      const int g = 2 * c;
      const uint32_t w0a = __shfl((int)dw[g][0], src0),
                     w0b = __shfl((int)dw[g + 1][0], src0);
      const uint32_t w1a = __shfl((int)dw[g][1], src0),
                     w1b = __shfl((int)dw[g + 1][1], src0);
      const uint32_t w2a = __shfl((int)dw[g][0], src1),
                     w2b = __shfl((int)dw[g + 1][0], src1);
      const uint32_t w3a = __shfl((int)dw[g][1], src1),
                     w3b = __shfl((int)dw[g + 1][1], src1);
      union { uint32_t u[4]; short8 s; } pa;
      pa.u[0] = hi ? w0b : w0a;
      pa.u[1] = hi ? w1b : w1a;
      pa.u[2] = hi ? w2b : w2a;
      pa.u[3] = hi ? w3b : w3a;
#pragma unroll
      for (int dg = 0; dg < 4; ++dg) {
        const int rowV = dg * 16 + lq;
        short8 vf = *(const short8*)((char*)lV + rowV * 128 +
                                     ((c * 64 + lh * 16) ^ ((lq & 7) << 4)));
        pv[dg] = __builtin_amdgcn_mfma_f32_16x16x32_bf16(pa.s, vf, pv[dg], 0, 0, 0);
      }
    }
  }

  // full-row l1, mc for q = lq (reduce across lh quarters)
  l1 += __shfl_xor(l1, 16); l1 += __shfl_xor(l1, 32);
  mc += __shfl_xor(mc, 16); mc += __shfl_xor(mc, 32);

  if (NSPLIT == 2) {
    float* pb = part + ((size_t)blockIdx.x) * PART_STRIDE;
#pragma unroll
    for (int r = 0; r < 4; ++r)
#pragma unroll
      for (int dg = 0; dg < 4; ++dg)
        pb[(w * 16 + 4 * lh + r) * 64 + dg * 16 + lq] = pv[dg][r];
    if (lh == 0) {
      pb[4096 + w * 16 + lq] = l1;
      pb[4160 + w * 16 + lq] = mc;
    }
  } else {
    const int b = bh / HH, h = bh - b * HH;
#pragma unroll
    for (int r = 0; r < 4; ++r) {
      const int qrow = 4 * lh + r;
      const float l1r = __shfl(l1, qrow);
      const float mcr = __shfl(mc, qrow);
      const float s1r = l1r - 0.5f * mcr;
      const float rden = 1.f / (2048.f * l1r + s1r);
      const int n = q0 + qrow;
#pragma unroll
      for (int dg = 0; dg < 4; ++dg) {
        const int d = dg * 16 + lq;
        const float csv = cs[bh * DD + d];
        const float val = (csv * l1r + pv[dg][r]) * rden;
        AO[((size_t)(b * NN + n)) * CC + h * DD + d] = f2bf(val);
      }
    }
  }
}

// ---------------------------------------------------------------------------
// Combine split-K partials -> AO (bf16).  Grid: 24*32 blocks, 256 thr.
// ---------------------------------------------------------------------------
__global__ __launch_bounds__(256)
void combine_k(const float* __restrict__ part, const float* __restrict__ cs,
               short* __restrict__ AO)
{
  const int bh = blockIdx.x >> 5;
  const int qblk = blockIdx.x & 31;
  const int t = threadIdx.x;
  const int q = t >> 2, dc = (t & 3) * 16;
  const float* pa_ = part + ((size_t)blockIdx.x * 2) * PART_STRIDE;
  const float* pb_ = pa_ + PART_STRIDE;
  const float l1 = pa_[4096 + q] + pb_[4096 + q];
  const float mcv = pa_[4160 + q] + pb_[4160 + q];
  const float s1 = l1 - 0.5f * mcv;
  const float rden = 1.f / (2048.f * l1 + s1);
  const int b = bh / HH, h = bh - b * HH;
  const int n = qblk * 64 + q;
  short* dst = AO + ((size_t)(b * NN + n)) * CC + h * DD + dc;
#pragma unroll
  for (int i = 0; i < 16; i += 4) {
    const int d = dc + i;
    f32x4 va = *(const f32x4*)(pa_ + q * 64 + d);
    f32x4 vb = *(const f32x4*)(pb_ + q * 64 + d);
    f32x4 cv = *(const f32x4*)(cs + bh * DD + d);
    short4v o;
#pragma unroll
    for (int e = 0; e < 4; ++e)
      o[e] = f2bf((cv[e] * l1 + va[e] + vb[e]) * rden);
    *(short4v*)(dst + i) = o;
  }
}

// ---------------------------------------------------------------------------
extern "C" void kernel_launch(void* const* d_in, const int* in_sizes, int n_in,
                              void* d_out, int out_size, void* d_ws, size_t ws_size,
                              hipStream_t stream)
{
  (void)in_sizes; (void)n_in; (void)out_size;
  float* out = (float*)d_out;

  const size_t HD = (size_t)2 * HH * NN * DD;   // 3,145,728 elements
  const size_t NX = 3145728, NW = 1769472, NO = 589824;
  const size_t base_need = (4 * HD + NX + NW + NO) * sizeof(short)
                         + (size_t)2 * HH * DD * sizeof(float) + 64;
  const size_t part_bytes = (size_t)1536 * PART_STRIDE * sizeof(float);
  if (ws_size < base_need) return;  // diagnostic: zero output -> absmax == max|ref|
  const bool use_split = ws_size >= base_need + part_bytes;

  short* Qb = (short*)d_ws;
  short* Kb = Qb + HD;
  short* VT = Kb + HD;
  short* AO = VT + HD;
  float* cs = (float*)(AO + HD);
  short* xb  = (short*)(cs + 2 * HH * DD);
  short* wqb = xb + NX;
  short* wob = wqb + NW;
  float* part = (float*)(wob + NO);

  dim3 blk(256);
  norm_k<<<dim3(2688), blk, 0, stream>>>((const float*)d_in[0],
                                         (const float*)d_in[1],
                                         (const float*)d_in[2],
                                         xb, wqb, wob);
  gemm_k<0><<<dim3(2304 / 128, 4096 / 128), blk, 0, stream>>>(
      xb, wqb, nullptr, Qb, Kb, VT, nullptr);
  colsum_k<<<dim3(2 * HH), blk, 0, stream>>>(VT, cs);
  if (use_split) {
    attn_k<2><<<dim3(2 * HH * 64), blk, 0, stream>>>(Qb, Kb, VT, cs, AO, part);
    combine_k<<<dim3(2 * HH * 32), blk, 0, stream>>>(part, cs, AO);
  } else {
    attn_k<1><<<dim3(2 * HH * 32), blk, 0, stream>>>(Qb, Kb, VT, cs, AO, nullptr);
  }
  gemm_k<1><<<dim3(CC / 128, 4096 / 128), blk, 0, stream>>>(
      AO, wob, (const float*)d_in[3], nullptr, nullptr, nullptr, out);
}